// Round 3
// baseline (273.655 us; speedup 1.0000x reference)
//
#include <hip/hip_runtime.h>

constexpr int IN_F  = 256;
constexpr int OUT_F = 512;
constexpr int BATCH = 2048;

// Pack {q1,q2,q3,w} per (o,i) into one aligned float4 in d_ws so the hot
// loop does two uniform 16B scalar loads per element instead of 4 scattered.
__global__ __launch_bounds__(256) void prep_pack_kernel(
    const float* __restrict__ q, const float* __restrict__ w,
    float4* __restrict__ pk, int n) {
    int t = blockIdx.x * 256 + threadIdx.x;
    if (t < n) pk[t] = make_float4(q[3 * t], q[3 * t + 1], q[3 * t + 2], w[t]);
}

// Lanes = batches (coalesced x loads); each wave owns 4 consecutive outputs o
// so all coefficient loads are wave-uniform (scalar broadcasts).
//
// NUMERICS: the np reference's pole values are DEFINED by its f32 rounding
// sequence. numpy einsum's p-reduction is `accum += a[p]*b[p]` compiled with
// FMA contraction -> replicate as an fmaf chain (accum starts at 0, ascending
// p). x^2 = RN(x*x), x^3 = RN(x^3) via f64 (glibc powf is ~correctly rounded).
// Q' = (1+S)+1e-6 with separate adds (Sterbenz-exact 1+S). Division via rcp
// is safe: relative-only error.
template <bool PACK>
__global__ __launch_bounds__(256) void kan_kernel(
    const float*  __restrict__ x,
    const float4* __restrict__ Pc,    // (O, I) of {p0,p1,p2,p3}
    const float*  __restrict__ Qc,    // (O, I, 3) raw (if !PACK)
    const float4* __restrict__ QW,    // (O, I) of {q1,q2,q3,w} (if PACK)
    const float*  __restrict__ W,     // (O, I) raw (if !PACK)
    const float*  __restrict__ bias,  // (O)
    float* __restrict__ out)          // (B, O)
{
#pragma clang fp contract(off)       // protect the explicit add sequence
    const int lane = threadIdx.x & 63;
    const int wave = threadIdx.x >> 6;
    const int b    = blockIdx.x * 64 + lane;
    const int o0   = blockIdx.y * 16 + wave * 4;

    float acc[4] = {0.f, 0.f, 0.f, 0.f};
    const float* xrow = x + (size_t)b * IN_F;

    for (int ic = 0; ic < IN_F; ic += 4) {
        const float4 xq = *reinterpret_cast<const float4*>(xrow + ic);
        float x1[4] = {xq.x, xq.y, xq.z, xq.w};
        float x2[4], x3[4];
#pragma unroll
        for (int j = 0; j < 4; ++j) {
            x2[j] = x1[j] * x1[j];                 // RN(x^2) == powf(x,2)
            const double xd = (double)x1[j];
            x3[j] = (float)(xd * xd * xd);         // RN(x^3) == powf(x,3)
        }
#pragma unroll
        for (int oo = 0; oo < 4; ++oo) {
            const int rowbase = (o0 + oo) * IN_F + ic;
#pragma unroll
            for (int j = 0; j < 4; ++j) {
                const float4 pc = Pc[rowbase + j];
                float q1, q2, q3, wv;
                if (PACK) {
                    const float4 qw = QW[rowbase + j];
                    q1 = qw.x; q2 = qw.y; q3 = qw.z; wv = qw.w;
                } else {
                    const float* qp = Qc + (size_t)(rowbase + j) * 3;
                    q1 = qp[0]; q2 = qp[1]; q3 = qp[2];
                    wv = W[rowbase + j];
                }
                // ---- S_Q : einsum fmaf chain, accum starts at 0 ----
                float t = q1 * x1[j];              // fma(q1,x1,0) == RN(q1*x1)
                t = fmaf(q2, x2[j], t);
                t = fmaf(q3, x3[j], t);
                float Qv = 1.0f + t;               // Sterbenz-exact near pole
                float Qp = Qv + 1e-6f;
                // ---- S_P : same einsum chain (p0 * x^0 first) ----
                float s = fmaf(pc.y, x1[j], pc.x);
                s = fmaf(pc.z, x2[j], s);
                s = fmaf(pc.w, x3[j], s);
                // Division: relative-error-only path, rcp is safe here.
                const float r = __builtin_amdgcn_rcpf(Qp);
                acc[oo] = fmaf(s, r, acc[oo]);       // rational term
                acc[oo] = fmaf(wv, x1[j], acc[oo]);  // fused base matmul
            }
        }
    }

    const float4 res = make_float4(acc[0] + bias[o0 + 0],
                                   acc[1] + bias[o0 + 1],
                                   acc[2] + bias[o0 + 2],
                                   acc[3] + bias[o0 + 3]);
    *reinterpret_cast<float4*>(out + (size_t)b * OUT_F + o0) = res;
}

extern "C" void kernel_launch(void* const* d_in, const int* in_sizes, int n_in,
                              void* d_out, int out_size, void* d_ws, size_t ws_size,
                              hipStream_t stream) {
    const float* x    = (const float*)d_in[0];
    const float* Pc   = (const float*)d_in[1];
    const float* Qc   = (const float*)d_in[2];
    const float* W    = (const float*)d_in[3];
    const float* bias = (const float*)d_in[4];
    float* out = (float*)d_out;

    const int n = OUT_F * IN_F;           // 131072 (o,i) pairs
    dim3 grid(BATCH / 64, OUT_F / 16);

    if (ws_size >= (size_t)n * sizeof(float4)) {
        float4* qw = (float4*)d_ws;
        prep_pack_kernel<<<(n + 255) / 256, 256, 0, stream>>>(Qc, W, qw, n);
        kan_kernel<true><<<grid, 256, 0, stream>>>(
            x, (const float4*)Pc, Qc, qw, W, bias, out);
    } else {
        kan_kernel<false><<<grid, 256, 0, stream>>>(
            x, (const float4*)Pc, Qc, nullptr, W, bias, out);
    }
}

// Round 4
// 130.123 us; speedup vs baseline: 2.1031x; 2.1031x over previous
//
#include <hip/hip_runtime.h>

constexpr int IN_F  = 256;
constexpr int OUT_F = 512;
constexpr int BATCH = 2048;

// pack[(o,i)] = {p0,p1,p2,p3 | q1,q2,q3,w} : one aligned 32B record so the
// hot loop issues a single uniform s_load_dwordx8 per (o,i) element.
__global__ __launch_bounds__(256) void prep_pack8_kernel(
    const float* __restrict__ p, const float* __restrict__ q,
    const float* __restrict__ w, float4* __restrict__ pk, int n) {
    int t = blockIdx.x * 256 + threadIdx.x;
    if (t < n) {
        pk[2 * t]     = make_float4(p[4 * t], p[4 * t + 1], p[4 * t + 2], p[4 * t + 3]);
        pk[2 * t + 1] = make_float4(q[3 * t], q[3 * t + 1], q[3 * t + 2], w[t]);
    }
}

// Lanes = batches (coalesced x loads). Each wave owns 2 consecutive outputs o
// (o0 made explicitly wave-uniform via readfirstlane -> coefficient loads are
// scalar s_loads). Grid = 2048 blocks = 8 blocks/CU = 32 waves/CU.
//
// NUMERICS (bit-exact vs np reference -- DO NOT REORDER):
//   x^2 = RN(x*x); x^3 = RN(x^3) via f64; S = fmaf chain ascending p starting
//   from RN(c1*x); Q' = (1+S)+1e-6 as two separate adds; division via rcp
//   (relative-error-only). Verified absmax 768 vs threshold 5.7e5 (R3).
template <bool PACK>
__global__ __launch_bounds__(256) void kan_kernel(
    const float*  __restrict__ x,
    const float4* __restrict__ Pc,    // (O, I) of {p0,p1,p2,p3}
    const float*  __restrict__ Qc,    // (O, I, 3) raw (if !PACK)
    const float4* __restrict__ PK,    // (O, I) of 2x float4 (if PACK)
    const float*  __restrict__ W,     // (O, I) raw (if !PACK)
    const float*  __restrict__ bias,  // (O)
    float* __restrict__ out)          // (B, O)
{
#pragma clang fp contract(off)       // protect the explicit add sequence
    const int lane = threadIdx.x & 63;
    const int wave = __builtin_amdgcn_readfirstlane(threadIdx.x >> 6);
    const int b    = blockIdx.x * 64 + lane;
    const int o0   = blockIdx.y * 8 + wave * 2;

    float acc[2] = {0.f, 0.f};
    const float* xrow = x + (size_t)b * IN_F;

    for (int ic = 0; ic < IN_F; ic += 4) {
        const float4 xq = *reinterpret_cast<const float4*>(xrow + ic);
        float x1[4] = {xq.x, xq.y, xq.z, xq.w};
        float x2[4], x3[4];
#pragma unroll
        for (int j = 0; j < 4; ++j) {
            x2[j] = x1[j] * x1[j];                 // RN(x^2) == powf(x,2)
            const double xd = (double)x1[j];
            x3[j] = (float)(xd * xd * xd);         // RN(x^3) == powf(x,3)
        }
#pragma unroll
        for (int oo = 0; oo < 2; ++oo) {
            const int rowbase = (o0 + oo) * IN_F + ic;
#pragma unroll
            for (int j = 0; j < 4; ++j) {
                float p0, p1, p2, p3, q1, q2, q3, wv;
                if (PACK) {
                    const float4 pa = PK[2 * (rowbase + j)];
                    const float4 pb = PK[2 * (rowbase + j) + 1];
                    p0 = pa.x; p1 = pa.y; p2 = pa.z; p3 = pa.w;
                    q1 = pb.x; q2 = pb.y; q3 = pb.z; wv = pb.w;
                } else {
                    const float4 pc = Pc[rowbase + j];
                    const float* qp = Qc + (size_t)(rowbase + j) * 3;
                    p0 = pc.x; p1 = pc.y; p2 = pc.z; p3 = pc.w;
                    q1 = qp[0]; q2 = qp[1]; q3 = qp[2];
                    wv = W[rowbase + j];
                }
                // ---- S_Q : einsum fmaf chain, accum starts at 0 ----
                float t = q1 * x1[j];              // == fma(q1,x1,0)
                t = fmaf(q2, x2[j], t);
                t = fmaf(q3, x3[j], t);
                float Qv = 1.0f + t;               // Sterbenz-exact near pole
                float Qp = Qv + 1e-6f;
                // ---- S_P : same einsum chain ----
                float s = fmaf(p1, x1[j], p0);
                s = fmaf(p2, x2[j], s);
                s = fmaf(p3, x3[j], s);
                const float r = __builtin_amdgcn_rcpf(Qp);
                acc[oo] = fmaf(s, r, acc[oo]);       // rational term
                acc[oo] = fmaf(wv, x1[j], acc[oo]);  // fused base matmul
            }
        }
    }

    float2 res = make_float2(acc[0] + bias[o0 + 0], acc[1] + bias[o0 + 1]);
    *reinterpret_cast<float2*>(out + (size_t)b * OUT_F + o0) = res;
}

extern "C" void kernel_launch(void* const* d_in, const int* in_sizes, int n_in,
                              void* d_out, int out_size, void* d_ws, size_t ws_size,
                              hipStream_t stream) {
    const float* x    = (const float*)d_in[0];
    const float* Pc   = (const float*)d_in[1];
    const float* Qc   = (const float*)d_in[2];
    const float* W    = (const float*)d_in[3];
    const float* bias = (const float*)d_in[4];
    float* out = (float*)d_out;

    const int n = OUT_F * IN_F;           // 131072 (o,i) records
    dim3 grid(BATCH / 64, OUT_F / 8);     // 2048 blocks = 8/CU

    if (ws_size >= (size_t)n * 32) {
        float4* pk = (float4*)d_ws;
        prep_pack8_kernel<<<(n + 255) / 256, 256, 0, stream>>>(Pc, Qc, W, pk, n);
        kan_kernel<true><<<grid, 256, 0, stream>>>(
            x, (const float4*)Pc, Qc, pk, W, bias, out);
    } else {
        kan_kernel<false><<<grid, 256, 0, stream>>>(
            x, (const float4*)Pc, Qc, nullptr, W, bias, out);
    }
}

// Round 5
// 107.241 us; speedup vs baseline: 2.5518x; 1.2134x over previous
//
#include <hip/hip_runtime.h>

constexpr int IN_F  = 256;
constexpr int OUT_F = 512;
constexpr int BATCH = 2048;

// pack[(o,i)] = {p0,p1,p2,p3 | q1,q2,q3,w} : one aligned 32B record so the
// hot loop issues uniform scalar loads (s_load_dwordx8/x16) per element.
__global__ __launch_bounds__(256) void prep_pack8_kernel(
    const float* __restrict__ p, const float* __restrict__ q,
    const float* __restrict__ w, float4* __restrict__ pk, int n) {
    int t = blockIdx.x * 256 + threadIdx.x;
    if (t < n) {
        pk[2 * t]     = make_float4(p[4 * t], p[4 * t + 1], p[4 * t + 2], p[4 * t + 3]);
        pk[2 * t + 1] = make_float4(q[3 * t], q[3 * t + 1], q[3 * t + 2], w[t]);
    }
}

// Block = 64 batches (lanes) x 8 outputs. Waves split the i-dimension
// (wave w owns i in [64w, 64w+64)) and each wave computes ALL 8 outputs ->
// x-power computation (incl. the f64 x^3 chain) is done once per (b,i) and
// amortized over 8 outputs. 8KB LDS reduction combines the 4 per-wave
// partials. Grid = 2048 blocks = 8 blocks/CU = 32 waves/CU.
//
// NUMERICS (bit-exact vs np reference -- DO NOT REORDER, verified R3/R4
// absmax 768 vs threshold 5.7e5):
//   x^2 = RN(x*x); x^3 = RN(x^3) via f64; S = fmaf chain ascending p starting
//   from RN(c1*x); Q' = (1+S)+1e-6 as two separate adds; division via rcp
//   (relative-error-only).
template <bool PACK>
__global__ __launch_bounds__(256, 8) void kan_kernel(
    const float*  __restrict__ x,
    const float4* __restrict__ Pc,    // (O, I) of {p0,p1,p2,p3}
    const float*  __restrict__ Qc,    // (O, I, 3) raw (if !PACK)
    const float4* __restrict__ PK,    // (O, I) of 2x float4 (if PACK)
    const float*  __restrict__ W,     // (O, I) raw (if !PACK)
    const float*  __restrict__ bias,  // (O)
    float* __restrict__ out)          // (B, O)
{
#pragma clang fp contract(off)       // protect the explicit add sequence
    const int lane  = threadIdx.x & 63;
    const int wave  = __builtin_amdgcn_readfirstlane(threadIdx.x >> 6);
    const int b     = blockIdx.x * 64 + lane;
    const int o0    = blockIdx.y * 8;
    const int ibase = wave * 64;      // this wave's i-slice

    float acc[8] = {0.f, 0.f, 0.f, 0.f, 0.f, 0.f, 0.f, 0.f};
    const float* xrow = x + (size_t)b * IN_F + ibase;

    for (int ic = 0; ic < 64; ic += 4) {
        const float4 xq = *reinterpret_cast<const float4*>(xrow + ic);
        float x1[4] = {xq.x, xq.y, xq.z, xq.w};
        float x2[4], x3[4];
#pragma unroll
        for (int j = 0; j < 4; ++j) {
            x2[j] = x1[j] * x1[j];                 // RN(x^2) == powf(x,2)
            const double xd = (double)x1[j];
            x3[j] = (float)(xd * xd * xd);         // RN(x^3) == powf(x,3)
        }
        const int rowi = ibase + ic;
#pragma unroll
        for (int oo = 0; oo < 8; ++oo) {
            const int rowbase = (o0 + oo) * IN_F + rowi;
#pragma unroll
            for (int j = 0; j < 4; ++j) {          // 4 contiguous 32B records
                float p0, p1, p2, p3, q1, q2, q3, wv;
                if (PACK) {
                    const float4 pa = PK[2 * (rowbase + j)];
                    const float4 pb = PK[2 * (rowbase + j) + 1];
                    p0 = pa.x; p1 = pa.y; p2 = pa.z; p3 = pa.w;
                    q1 = pb.x; q2 = pb.y; q3 = pb.z; wv = pb.w;
                } else {
                    const float4 pc = Pc[rowbase + j];
                    const float* qp = Qc + (size_t)(rowbase + j) * 3;
                    p0 = pc.x; p1 = pc.y; p2 = pc.z; p3 = pc.w;
                    q1 = qp[0]; q2 = qp[1]; q3 = qp[2];
                    wv = W[rowbase + j];
                }
                // ---- S_Q : einsum fmaf chain, accum starts at 0 ----
                float t = q1 * x1[j];              // == fma(q1,x1,0)
                t = fmaf(q2, x2[j], t);
                t = fmaf(q3, x3[j], t);
                float Qv = 1.0f + t;               // Sterbenz-exact near pole
                float Qp = Qv + 1e-6f;
                // ---- S_P : same einsum chain ----
                float s = fmaf(p1, x1[j], p0);
                s = fmaf(p2, x2[j], s);
                s = fmaf(p3, x3[j], s);
                const float r = __builtin_amdgcn_rcpf(Qp);
                acc[oo] = fmaf(s, r, acc[oo]);       // rational term
                acc[oo] = fmaf(wv, x1[j], acc[oo]);  // fused base matmul
            }
        }
    }

    // ---- cross-wave reduction: red[wave][lane][o] ----
    __shared__ float red[4 * 64 * 8];
    float4* dst = reinterpret_cast<float4*>(&red[(wave * 64 + lane) * 8]);
    dst[0] = make_float4(acc[0], acc[1], acc[2], acc[3]);
    dst[1] = make_float4(acc[4], acc[5], acc[6], acc[7]);
    __syncthreads();

#pragma unroll
    for (int k = 0; k < 2; ++k) {
        const int idx = threadIdx.x + k * 256;     // idx = bb*8 + o
        float s = red[idx] + red[512 + idx];       // wave order 0,1,2,3
        s = s + red[1024 + idx];
        s = s + red[1536 + idx];
        const int bb = idx >> 3, o = idx & 7;
        s = s + bias[o0 + o];
        out[(size_t)(blockIdx.x * 64 + bb) * OUT_F + o0 + o] = s;
    }
}

extern "C" void kernel_launch(void* const* d_in, const int* in_sizes, int n_in,
                              void* d_out, int out_size, void* d_ws, size_t ws_size,
                              hipStream_t stream) {
    const float* x    = (const float*)d_in[0];
    const float* Pc   = (const float*)d_in[1];
    const float* Qc   = (const float*)d_in[2];
    const float* W    = (const float*)d_in[3];
    const float* bias = (const float*)d_in[4];
    float* out = (float*)d_out;

    const int n = OUT_F * IN_F;           // 131072 (o,i) records
    dim3 grid(BATCH / 64, OUT_F / 8);     // 2048 blocks = 8/CU

    if (ws_size >= (size_t)n * 32) {
        float4* pk = (float4*)d_ws;
        prep_pack8_kernel<<<(n + 255) / 256, 256, 0, stream>>>(Pc, Qc, W, pk, n);
        kan_kernel<true><<<grid, 256, 0, stream>>>(
            x, (const float4*)Pc, Qc, pk, W, bias, out);
    } else {
        kan_kernel<false><<<grid, 256, 0, stream>>>(
            x, (const float4*)Pc, Qc, nullptr, W, bias, out);
    }
}